// Round 8
// baseline (113.352 us; speedup 1.0000x reference)
//
#include <hip/hip_runtime.h>
#include <hip/hip_fp8.h>

#define BB 8
#define NN 4096
#define MM 4096
#define DD 128

typedef float f32x4  __attribute__((ext_vector_type(4)));
typedef float f32x16 __attribute__((ext_vector_type(16)));
typedef int   i32x4  __attribute__((ext_vector_type(4)));
typedef int   i32x8  __attribute__((ext_vector_type(8)));

// ---------------------------------------------------------------------------
// R28: FORCE the x prefetch. R27 evidence: VGPR_Count=60 — the compiler
// sank the ring-of-3 loads back to point-of-use (48 VGPR ring cannot live
// in 60), so the prefetch never existed; main 46.2us, ~860 cyc/SIMD per
// wave-batch vs ~370 pipe demand -> ~490 cyc latency stall. Depth-1 held
// prefetch is sufficient by Little's law (4KB/wave x 16 waves/CU = 64KB/CU
// in flight >> ~30KB needed for the 34.5 TB/s L2 ceiling) — it just has to
// actually be ISSUED a batch early.
// Fix (guide T4 / rule 18): x loads via asm volatile global_load_dwordx4
// into a reg ring-of-2 (volatile asm cannot be sunk), consumption gated by
// s_waitcnt vmcnt(4) (vmcnt(0) last batch) expressed as asm tying the fx
// values ("+v") + sched_barrier(0) so hipcc can't hoist the MFMAs past it.
// vmcnt arithmetic exact: only in-loop vmem is these 4 loads/iter (y was
// drained by the prologue barrier; fbuf atomics are DS).
// Everything else identical to R27 (absmax 0 throughout this lineage).
//
// Fixed harness cost: ~45us 256MiB fillBufferAligned re-poison in-window.
//
// R19-27 retained: fragment-ordered fp8, HALF-norms + negated y (acc=sq/2),
// mfma_scale_f32_32x32x64_f8f6f4 identity scale, balanced per-XCD patch,
// coalesced LDS-staged prep, all-y-staged prologue, barrier-free loop.
// LESSONS: merged finalize regresses (R11/12/15/16); cooperative launch
// fails (R14); prep transport not the gap (R21); per-batch barriers cost
// ~2x at low occ (R23); spills catastrophic (R24); TLP alone insufficient
// (R26); PLAIN-HIP PREFETCH GETS SUNK BY THE COMPILER (R27, VGPR=60).
// ---------------------------------------------------------------------------

typedef const __attribute__((address_space(1))) unsigned int* gas_ptr;
typedef __attribute__((address_space(3))) unsigned int* las_ptr;
static __device__ __forceinline__ void gload_lds16(const unsigned char* g,
                                                   unsigned char* l) {
    __builtin_amdgcn_global_load_lds((gas_ptr)g, (las_ptr)l, 16, 0, 0);
}

// Issue the 4 x-fragment loads for one batch into a held register quad set.
// Volatile asm: cannot be sunk or deleted. Early-clobber so the addr pair
// is never allocated inside an output quad.
#define ISSUE_X(dst, addr)                                                  \
    asm volatile("global_load_dwordx4 %0, %4, off\n\t"                      \
                 "global_load_dwordx4 %1, %4, off offset:16\n\t"            \
                 "global_load_dwordx4 %2, %4, off offset:2048\n\t"          \
                 "global_load_dwordx4 %3, %4, off offset:2064"              \
                 : "=&v"(dst[0]), "=&v"(dst[1]), "=&v"(dst[2]), "=&v"(dst[3]) \
                 : "v"(addr))

// Gate consumption of a batch's x-frags: wait until <=N vmem outstanding,
// tying the values so the consumers cannot be hoisted above the wait.
#define WAIT_X(buf, N)                                                      \
    do {                                                                    \
        asm volatile("s_waitcnt vmcnt(" #N ")"                              \
                     : "+v"(buf[0]), "+v"(buf[1]), "+v"(buf[2]), "+v"(buf[3])); \
        __builtin_amdgcn_sched_barrier(0);                                  \
    } while (0)

// Prep v2 (R21, unchanged): 2048 blocks x 256 threads, one 32-row fragment
// group (4KB) per block; coalesced reads -> cvt -> LDS permute -> coalesced
// 16B stores. Also inits fwd/bsum/fsum/counter and writes half-norms.
__global__ __launch_bounds__(256)
void prep_all(const float* __restrict__ x, const float* __restrict__ y,
              unsigned char* __restrict__ xq, unsigned char* __restrict__ yq,
              float* __restrict__ x2, float* __restrict__ y2,
              unsigned int* __restrict__ fwd, float* __restrict__ bsum,
              float* __restrict__ fsum, unsigned int* __restrict__ counter) {
    __shared__ i32x4 lbuf[256];  // 4 KB fragment-ordered staging

    const int tid  = threadIdx.x;
    const int g    = blockIdx.x;
    const int gtid = g * 256 + tid;
    if (gtid < BB * MM) fwd[gtid] = 0x7f800000u;  // +inf bits
    if (gtid == 0) { *bsum = 0.0f; *fsum = 0.0f; *counter = 0u; }

    const int rl = tid >> 3;   // row within group (0..31)
    const int c  = tid & 7;    // 16-float chunk within row (0..7)

    const float* src;
    unsigned char* dst;
    float* sq;
    float sgn;
    int row;
    if (g < 1024) {
        src = x; dst = xq + (size_t)g * 4096; sq = x2; sgn = 1.0f;
        row = g * 32 + rl;
    } else {
        src = y; dst = yq + (size_t)(g - 1024) * 4096; sq = y2; sgn = -1.0f;
        row = (g - 1024) * 32 + rl;
    }

    const f32x4* base = (const f32x4*)(src + (size_t)row * DD + c * 16);
    f32x4 v[4];
    #pragma unroll
    for (int j = 0; j < 4; ++j) v[j] = base[j];

    float s = 0.0f;
    #pragma unroll
    for (int j = 0; j < 4; ++j)
        s += v[j].x * v[j].x + v[j].y * v[j].y + v[j].z * v[j].z + v[j].w * v[j].w;

    i32x4 d;
    #pragma unroll
    for (int j = 0; j < 4; ++j) {
        unsigned int dj = (unsigned int)__builtin_amdgcn_cvt_pk_fp8_f32(
            sgn * v[j].x, sgn * v[j].y, 0, false);
        dj = (unsigned int)__builtin_amdgcn_cvt_pk_fp8_f32(
            sgn * v[j].z, sgn * v[j].w, (int)dj, true);
        d[j] = (int)dj;
    }

    const int lds_off = (c >> 2) * 2048 + ((c >> 1) & 1) * 1024
                      + rl * 32 + (c & 1) * 16;
    *(i32x4*)((char*)lbuf + lds_off) = d;

    #pragma unroll
    for (int m = 4; m; m >>= 1) s += __shfl_xor(s, m, 64);
    if (c == 0) sq[row] = 0.5f * s;

    __syncthreads();
    *(i32x4*)(dst + (size_t)tid * 16) = lbuf[tid];
}

// ---------------------------------------------------------------------------
// Main v8: 4096 blocks (128n x 32m), 4 waves of 32n x 32m, all-y-staged
// prologue, barrier-free loop, ASM-FORCED depth-1 x prefetch (reg ring-of-2).
// ---------------------------------------------------------------------------
__global__ __launch_bounds__(256, 4)
void chamfer_main(const unsigned char* __restrict__ xq, const unsigned char* __restrict__ yq,
                  const float* __restrict__ x2, const float* __restrict__ y2,
                  unsigned int* __restrict__ fwd, float* __restrict__ bpart) {
    __shared__ float x2s[BB][128];            // 4 KB
    __shared__ float y2s[BB][32];             // 1 KB
    __shared__ unsigned int fbuf[BB][32];     // 1 KB
    __shared__ unsigned char ybuf[BB][4096];  // 32 KB: ALL batches of y-frags
    __shared__ float red[4];

    const int tid   = threadIdx.x;
    const int lane  = tid & 63;
    const int wave  = tid >> 6;    // 0..3
    const int lhalf = lane >> 5;
    const int l31   = lane & 31;

    const int id  = blockIdx.x;
    const int xcd = id & 7;
    const int j   = id >> 3;                   // 0..511
    const int nb  = (xcd >> 1) * 8 + (j & 7);  // 0..31   (128 n each)
    const int mb  = (xcd & 1) * 64 + (j >> 3); // 0..127  (32 m each)
    const int n0b = nb * 128;
    const int n0w = n0b + wave * 32;
    const int m0  = mb * 32;

    // x fragment base (per-wave registers)
    const size_t laneoff = (size_t)lhalf * 1024 + (size_t)l31 * 32;
    const unsigned char* xbase = xq + (size_t)(n0w >> 5) * 4096 + laneoff;

    // y staging, source-swizzled so LDS is dense (R22-verified formula,
    // single group): wave w stages chunk w; lane -> row l31, 16B-half lhalf.
    const size_t ysw = (size_t)(wave >> 1) * 2048 + (size_t)(wave & 1) * 1024
                     + ((size_t)lhalf << 4) + (size_t)l31 * 32;
    const unsigned char* ybase = yq + (size_t)mb * 4096 + ysw;

    // prologue: stage ALL 8 batches of y (1 gload_lds per wave per batch)
    #pragma unroll
    for (int b = 0; b < BB; ++b)
        gload_lds16(ybase + ((size_t)b << 19), &ybuf[b][wave * 1024]);

    // x ring-of-2, asm-held: fxr[buf][0..3] = {i0h0, i0h1(+16), i1h0(+2048),
    // i1h1(+2064)}; batch b's base = xbase + b*512KB.
    i32x4 fxr[2][4];
    ISSUE_X(fxr[0], xbase);   // batch 0 (drained by the prologue barrier)

    for (int i = tid; i < BB * 128; i += 256)
        x2s[i >> 7][i & 127] = x2[(size_t)(i >> 7) * NN + n0b + (i & 127)];
    {
        int i = tid;  // exactly BB*32 = 256 items
        y2s[i >> 5][i & 31] = y2[(size_t)(i >> 5) * MM + m0 + (i & 31)];
        ((unsigned int*)fbuf)[i] = 0x7f800000u;
    }
    __syncthreads();  // drains ALL staging (vmcnt 0): y LDS + batch-0 x regs

    const float INF = __builtin_inff();
    float bmin[16];  // running min of acc = sq/2
    #pragma unroll
    for (int r = 0; r < 16; ++r) bmin[r] = INF;

    const int rb0 = lhalf * 1024 + l31 * 16;  // dense y read base

    #pragma unroll   // FULL unroll: ring indices compile-time
    for (int b = 0; b < BB; ++b) {
        const int cur = b & 1;
        // issue next batch's x FIRST (volatile: stays here, stays issued)
        if (b < BB - 1)
            ISSUE_X(fxr[cur ^ 1], (xbase + ((size_t)(b + 1) << 19)));

        // gate batch b's x: oldest 4 loads must be done; next-batch 4 stay
        // in flight across the whole compute phase below.
        if (b < BB - 1) { WAIT_X(fxr[cur], 4); }
        else            { WAIT_X(fxr[cur], 0); }

        // acc seed: (x2+y2)/2 -> MFMA (neg-y fp8) yields acc = sq/2
        // C/D: col = l31, row = (r&3) + 8*(r>>2) + 4*lhalf
        float y2v = y2s[b][l31];
        f32x16 acc;
        #pragma unroll
        for (int q = 0; q < 4; ++q) {
            f32x4 xv = *(const f32x4*)&x2s[b][wave * 32 + lhalf * 4 + q * 8];
            #pragma unroll
            for (int e = 0; e < 4; ++e)
                acc[q * 4 + e] = xv[e] + y2v;
        }

        #pragma unroll
        for (int i = 0; i < 2; ++i) {
            i32x8 av = __builtin_shufflevector(fxr[cur][2 * i], fxr[cur][2 * i + 1],
                                               0, 1, 2, 3, 4, 5, 6, 7);
            const unsigned char* yb = &ybuf[b][i * 2048 + rb0];
            i32x4 lo = *(const i32x4*)(yb);
            i32x4 hi = *(const i32x4*)(yb + 512);
            i32x8 bv = __builtin_shufflevector(lo, hi, 0, 1, 2, 3, 4, 5, 6, 7);
            acc = __builtin_amdgcn_mfma_scale_f32_32x32x64_f8f6f4(
                av, bv, acc, 0, 0, 0, 127, 0, 127);
        }

        // epilogue: pure fmin (acc IS sq/2)
        float fm = INF;
        #pragma unroll
        for (int r = 0; r < 16; ++r) {
            bmin[r] = fminf(bmin[r], acc[r]);
            fm      = fminf(fm, acc[r]);
        }
        // clamp >=0 so uint ordering == float ordering; lanes l/l+32 share
        // an address (2-way): no-return ds_min, pipelined
        atomicMin(&fbuf[b][l31], __float_as_uint(fmaxf(fm, 0.0f)));
    }
    __syncthreads();  // fbuf atomics from all waves complete

    // flush forward mins (values are sq/2; finalize applies the 2x)
    {
        int i = tid;  // exactly BB*32 = 256 items
        atomicMin(&fwd[(size_t)(i >> 5) * MM + m0 + (i & 31)], fbuf[i >> 5][i & 31]);
    }

    // backward: sqrt(2 * clamp(min sq/2)), block-reduce, one store/block
    float s = 0.0f;
    #pragma unroll
    for (int r = 0; r < 16; ++r)
        s += sqrtf(2.0f * fmaxf(bmin[r], 0.0f));
    #pragma unroll
    for (int off = 32; off; off >>= 1) s += __shfl_down(s, off, 64);
    if (lane == 0) red[wave] = s;
    __syncthreads();
    if (tid == 0) bpart[id] = red[0] + red[1] + red[2] + red[3];
}

// Finalize: 32 blocks x 256 threads. fwd holds min sq/2 -> dist = sqrt(2v).
__global__ __launch_bounds__(256)
void finalize_kernel(const unsigned int* __restrict__ fwd,
                     const float* __restrict__ bpart,
                     float* __restrict__ bsum, float* __restrict__ fsum,
                     unsigned int* __restrict__ counter, float* __restrict__ out) {
    __shared__ float redf[4], redb[4];
    __shared__ int isLast;
    const int tid = threadIdx.x, lane = tid & 63, wave = tid >> 6;
    const int gtid = blockIdx.x * 256 + tid;
    uint4 u = ((const uint4*)fwd)[gtid];
    float sf = sqrtf(2.0f * __uint_as_float(u.x)) + sqrtf(2.0f * __uint_as_float(u.y)) +
               sqrtf(2.0f * __uint_as_float(u.z)) + sqrtf(2.0f * __uint_as_float(u.w));
    float sb = (gtid < 4096) ? bpart[gtid] : 0.0f;   // 4096 main blocks
    #pragma unroll
    for (int off = 32; off; off >>= 1) {
        sf += __shfl_down(sf, off, 64);
        sb += __shfl_down(sb, off, 64);
    }
    if (lane == 0) { redf[wave] = sf; redb[wave] = sb; }
    __syncthreads();
    if (tid == 0) {
        atomicAdd(fsum, redf[0] + redf[1] + redf[2] + redf[3]);
        atomicAdd(bsum, redb[0] + redb[1] + redb[2] + redb[3]);
        __threadfence();
        unsigned int c = atomicAdd(counter, 1u);
        isLast = (c == gridDim.x - 1) ? 1 : 0;
        if (isLast) {
            __threadfence();
            float fs = __hip_atomic_load(fsum, __ATOMIC_RELAXED,
                                         __HIP_MEMORY_SCOPE_AGENT);
            float bs = __hip_atomic_load(bsum, __ATOMIC_RELAXED,
                                         __HIP_MEMORY_SCOPE_AGENT);
            out[0] = fs / (float)(BB * MM) + bs / ((float)NN * (float)MM);
        }
    }
}

extern "C" void kernel_launch(void* const* d_in, const int* in_sizes, int n_in,
                              void* d_out, int out_size, void* d_ws, size_t ws_size,
                              hipStream_t stream) {
    const float* x = (const float*)d_in[0];  // (B,N,D)
    const float* y = (const float*)d_in[1];  // (B,M,D)
    float* out = (float*)d_out;

    char* w = (char*)d_ws;
    unsigned char* xq = (unsigned char*)(w);               // 4 MB fp8 (frag order)
    unsigned char* yq = (unsigned char*)(w + 4194304);     // 4 MB fp8, NEGATED
    float*    x2 = (float*)(w + 8388608);                  // 128 KB (x2/2)
    float*    y2 = (float*)(w + 8519680);                  // 128 KB (y2/2)
    unsigned int* fwd = (unsigned int*)(w + 8650752);      // 128 KB (min sq/2)
    float*    bpart = (float*)(w + 8781824);               // 16 KB (4096 blocks)
    float*    bsum = (float*)(w + 8798208);                // 4 B
    float*    fsum = (float*)(w + 8798212);                // 4 B
    unsigned int* counter = (unsigned int*)(w + 8798216);  // 4 B

    prep_all<<<2048, 256, 0, stream>>>(x, y, xq, yq, x2, y2,
                                       fwd, bsum, fsum, counter);
    chamfer_main<<<4096, 256, 0, stream>>>(xq, yq, x2, y2, fwd, bpart);
    finalize_kernel<<<32, 256, 0, stream>>>(fwd, bpart, bsum, fsum, counter, out);
}

// Round 9
// 112.436 us; speedup vs baseline: 1.0081x; 1.0081x over previous
//
#include <hip/hip_runtime.h>
#include <hip/hip_fp8.h>

#define BB 8
#define NN 4096
#define MM 4096
#define DD 128

typedef float f32x4  __attribute__((ext_vector_type(4)));
typedef float f32x16 __attribute__((ext_vector_type(16)));
typedef int   i32x4  __attribute__((ext_vector_type(4)));
typedef int   i32x8  __attribute__((ext_vector_type(8)));

// ---------------------------------------------------------------------------
// R29: amortize the per-tile fixed costs — wave goes 32n -> 64n x 32m.
// Evidence: R26 (TLP 2x), R27 (ring-3, sunk), R28 (asm-held prefetch) ALL
// land main at 42-46us -> latency/scheduling is NOT the binder. What is
// config-invariant: per-32x32-tile fixed costs (4 y ds_read_b128, seed LDS
// reads, 1 ds-atomic, waitcnt, loop bookkeeping) and the 512MB of y pulled
// through LDS (every wave reads its full y operand per batch).
// Fix: wave computes TWO n-groups with the SAME y registers: 4 ds_read_b128
// now feed 4 MFMAs (was 2) -> y LDS traffic, atomics, waitcnts, bookkeeping
// per unit work all HALVE; per-wave ILP doubles (2 independent acc chains),
// compensating the 2-waves/SIMD occupancy (VGPR ~170 < 256 cap of (256,2);
// R25 proved 2 waves/SIMD viable). Block = 256n x 32m (4 waves), 2048
// blocks, balanced XCD patch (1MB x + 2MB y per XCD < 4MB L2).
// x prefetch: R28's asm-held ring-of-2, 8 loads/batch, vmcnt(8) gate
// (exact: only in-loop vmem). Spill tripwire: WRITE_SIZE (R24: 118MB).
//
// Fixed harness cost: ~45us 256MiB fillBufferAligned re-poison in-window.
//
// R19-28 retained: fragment-ordered fp8 (absmax 0 throughout), HALF-norms +
// negated y (acc=sq/2), mfma_scale_f32_32x32x64_f8f6f4 identity scale 127,
// coalesced LDS-staged prep, all-y-staged prologue, barrier-free loop.
// LESSONS: merged finalize regresses (R11/12/15/16); cooperative launch
// fails (R14); prep transport not the gap (R21); per-batch barriers ~2x at
// low occ (R23); spills catastrophic (R24); TLP alone null (R26); compiler
// sinks plain-HIP prefetch (R27, VGPR=60); forced prefetch null (R28).
// ---------------------------------------------------------------------------

typedef const __attribute__((address_space(1))) unsigned int* gas_ptr;
typedef __attribute__((address_space(3))) unsigned int* las_ptr;
static __device__ __forceinline__ void gload_lds16(const unsigned char* g,
                                                   unsigned char* l) {
    __builtin_amdgcn_global_load_lds((gas_ptr)g, (las_ptr)l, 16, 0, 0);
}

// Issue the 4 x-fragment loads for one 32-row group into held registers.
// Volatile asm: cannot be sunk or deleted.
#define ISSUE_X(dst, addr)                                                  \
    asm volatile("global_load_dwordx4 %0, %4, off\n\t"                      \
                 "global_load_dwordx4 %1, %4, off offset:16\n\t"            \
                 "global_load_dwordx4 %2, %4, off offset:2048\n\t"          \
                 "global_load_dwordx4 %3, %4, off offset:2064"              \
                 : "=&v"(dst[0]), "=&v"(dst[1]), "=&v"(dst[2]), "=&v"(dst[3]) \
                 : "v"(addr))

// Gate consumption of a batch's 8 x-frag loads (both n-groups): wait until
// <=N vmem outstanding, tying all 8 values so consumers can't be hoisted.
#define WAIT_X8(a, c, N)                                                    \
    do {                                                                    \
        asm volatile("s_waitcnt vmcnt(" #N ")"                              \
                     : "+v"(a[0]), "+v"(a[1]), "+v"(a[2]), "+v"(a[3]),      \
                       "+v"(c[0]), "+v"(c[1]), "+v"(c[2]), "+v"(c[3]));     \
        __builtin_amdgcn_sched_barrier(0);                                  \
    } while (0)

// Prep v2 (R21, unchanged): 2048 blocks x 256 threads, one 32-row fragment
// group (4KB) per block; coalesced reads -> cvt -> LDS permute -> coalesced
// 16B stores. Also inits fwd/bsum/fsum/counter and writes half-norms.
__global__ __launch_bounds__(256)
void prep_all(const float* __restrict__ x, const float* __restrict__ y,
              unsigned char* __restrict__ xq, unsigned char* __restrict__ yq,
              float* __restrict__ x2, float* __restrict__ y2,
              unsigned int* __restrict__ fwd, float* __restrict__ bsum,
              float* __restrict__ fsum, unsigned int* __restrict__ counter) {
    __shared__ i32x4 lbuf[256];  // 4 KB fragment-ordered staging

    const int tid  = threadIdx.x;
    const int g    = blockIdx.x;
    const int gtid = g * 256 + tid;
    if (gtid < BB * MM) fwd[gtid] = 0x7f800000u;  // +inf bits
    if (gtid == 0) { *bsum = 0.0f; *fsum = 0.0f; *counter = 0u; }

    const int rl = tid >> 3;   // row within group (0..31)
    const int c  = tid & 7;    // 16-float chunk within row (0..7)

    const float* src;
    unsigned char* dst;
    float* sq;
    float sgn;
    int row;
    if (g < 1024) {
        src = x; dst = xq + (size_t)g * 4096; sq = x2; sgn = 1.0f;
        row = g * 32 + rl;
    } else {
        src = y; dst = yq + (size_t)(g - 1024) * 4096; sq = y2; sgn = -1.0f;
        row = (g - 1024) * 32 + rl;
    }

    const f32x4* base = (const f32x4*)(src + (size_t)row * DD + c * 16);
    f32x4 v[4];
    #pragma unroll
    for (int j = 0; j < 4; ++j) v[j] = base[j];

    float s = 0.0f;
    #pragma unroll
    for (int j = 0; j < 4; ++j)
        s += v[j].x * v[j].x + v[j].y * v[j].y + v[j].z * v[j].z + v[j].w * v[j].w;

    i32x4 d;
    #pragma unroll
    for (int j = 0; j < 4; ++j) {
        unsigned int dj = (unsigned int)__builtin_amdgcn_cvt_pk_fp8_f32(
            sgn * v[j].x, sgn * v[j].y, 0, false);
        dj = (unsigned int)__builtin_amdgcn_cvt_pk_fp8_f32(
            sgn * v[j].z, sgn * v[j].w, (int)dj, true);
        d[j] = (int)dj;
    }

    const int lds_off = (c >> 2) * 2048 + ((c >> 1) & 1) * 1024
                      + rl * 32 + (c & 1) * 16;
    *(i32x4*)((char*)lbuf + lds_off) = d;

    #pragma unroll
    for (int m = 4; m; m >>= 1) s += __shfl_xor(s, m, 64);
    if (c == 0) sq[row] = 0.5f * s;

    __syncthreads();
    *(i32x4*)(dst + (size_t)tid * 16) = lbuf[tid];
}

// ---------------------------------------------------------------------------
// Main v9: 2048 blocks (256n x 32m), 4 waves of 64n x 32m. All-y-staged
// prologue, barrier-free loop, asm-held x prefetch, y regs feed 4 MFMAs.
// ---------------------------------------------------------------------------
__global__ __launch_bounds__(256, 2)
void chamfer_main(const unsigned char* __restrict__ xq, const unsigned char* __restrict__ yq,
                  const float* __restrict__ x2, const float* __restrict__ y2,
                  unsigned int* __restrict__ fwd, float* __restrict__ bpart) {
    __shared__ float x2s[BB][256];            // 8 KB
    __shared__ float y2s[BB][32];             // 1 KB
    __shared__ unsigned int fbuf[BB][32];     // 1 KB
    __shared__ unsigned char ybuf[BB][4096];  // 32 KB: ALL batches of y-frags
    __shared__ float red[4];

    const int tid   = threadIdx.x;
    const int lane  = tid & 63;
    const int wave  = tid >> 6;    // 0..3
    const int lhalf = lane >> 5;
    const int l31   = lane & 31;

    const int id  = blockIdx.x;
    const int xcd = id & 7;
    const int j   = id >> 3;                   // 0..255
    const int nb  = (xcd >> 1) * 4 + (j & 3);  // 0..15   (256 n each)
    const int mb  = (xcd & 1) * 64 + (j >> 2); // 0..127  (32 m each)
    const int n0b = nb * 256;
    const int n0w = n0b + wave * 64;           // wave covers 64 n
    const int m0  = mb * 32;

    // x fragment base (per-wave registers); n-group g at +g*4096
    const size_t laneoff = (size_t)lhalf * 1024 + (size_t)l31 * 32;
    const unsigned char* xbase = xq + (size_t)(n0w >> 5) * 4096 + laneoff;

    // y staging, source-swizzled so LDS is dense (R22-verified formula,
    // single group): wave w stages chunk w; lane -> row l31, 16B-half lhalf.
    const size_t ysw = (size_t)(wave >> 1) * 2048 + (size_t)(wave & 1) * 1024
                     + ((size_t)lhalf << 4) + (size_t)l31 * 32;
    const unsigned char* ybase = yq + (size_t)mb * 4096 + ysw;

    // prologue: stage ALL 8 batches of y (1 gload_lds per wave per batch)
    #pragma unroll
    for (int b = 0; b < BB; ++b)
        gload_lds16(ybase + ((size_t)b << 19), &ybuf[b][wave * 1024]);

    // x ring-of-2 x 2 n-groups, asm-held:
    // fxr[buf][g][0..3] = {i0h0, i0h1(+16), i1h0(+2048), i1h1(+2064)}
    i32x4 fxr[2][2][4];
    ISSUE_X(fxr[0][0], xbase);           // batch 0, group 0
    ISSUE_X(fxr[0][1], (xbase + 4096));  // batch 0, group 1

    for (int i = tid; i < BB * 256; i += 256)
        x2s[i >> 8][i & 255] = x2[(size_t)(i >> 8) * NN + n0b + (i & 255)];
    {
        int i = tid & 255;  // exactly BB*32 = 256 items
        y2s[i >> 5][i & 31] = y2[(size_t)(i >> 5) * MM + m0 + (i & 31)];
        ((unsigned int*)fbuf)[i] = 0x7f800000u;
    }
    __syncthreads();  // drains ALL staging (vmcnt 0): y LDS + batch-0 x regs

    const float INF = __builtin_inff();
    float bmin[2][16];  // [n-group][reg] running min of acc = sq/2
    #pragma unroll
    for (int g = 0; g < 2; ++g)
        #pragma unroll
        for (int r = 0; r < 16; ++r) bmin[g][r] = INF;

    const int rb0 = lhalf * 1024 + l31 * 16;  // dense y read base

    #pragma unroll   // FULL unroll: ring indices compile-time
    for (int b = 0; b < BB; ++b) {
        const int cur = b & 1;
        // issue next batch's 8 x loads FIRST (volatile: stays issued here)
        if (b < BB - 1) {
            const unsigned char* xb = xbase + ((size_t)(b + 1) << 19);
            ISSUE_X(fxr[cur ^ 1][0], xb);
            ISSUE_X(fxr[cur ^ 1][1], (xb + 4096));
        }
        // gate batch b's x: its 8 loads done; next-batch 8 stay in flight
        if (b < BB - 1) { WAIT_X8(fxr[cur][0], fxr[cur][1], 8); }
        else            { WAIT_X8(fxr[cur][0], fxr[cur][1], 0); }

        // acc seed: (x2+y2)/2 -> MFMA (neg-y fp8) yields acc = sq/2
        // C/D: col = l31, row = (r&3) + 8*(r>>2) + 4*lhalf  (within group g)
        float y2v = y2s[b][l31];
        f32x16 acc[2];
        #pragma unroll
        for (int g = 0; g < 2; ++g)
            #pragma unroll
            for (int q = 0; q < 4; ++q) {
                f32x4 xv = *(const f32x4*)
                    &x2s[b][wave * 64 + g * 32 + lhalf * 4 + q * 8];
                #pragma unroll
                for (int e = 0; e < 4; ++e)
                    acc[g][q * 4 + e] = xv[e] + y2v;
            }

        // 4 MFMAs per batch; y regs (by) shared across both n-groups
        #pragma unroll
        for (int i = 0; i < 2; ++i) {
            const unsigned char* yb = &ybuf[b][i * 2048 + rb0];
            i32x4 lo = *(const i32x4*)(yb);
            i32x4 hi = *(const i32x4*)(yb + 512);
            i32x8 bv = __builtin_shufflevector(lo, hi, 0, 1, 2, 3, 4, 5, 6, 7);
            #pragma unroll
            for (int g = 0; g < 2; ++g) {
                i32x8 av = __builtin_shufflevector(fxr[cur][g][2 * i],
                                                   fxr[cur][g][2 * i + 1],
                                                   0, 1, 2, 3, 4, 5, 6, 7);
                acc[g] = __builtin_amdgcn_mfma_scale_f32_32x32x64_f8f6f4(
                    av, bv, acc[g], 0, 0, 0, 127, 0, 127);
            }
        }

        // epilogue: pure fmin (acc IS sq/2); ONE ds-atomic per wave-batch
        float fm = INF;
        #pragma unroll
        for (int g = 0; g < 2; ++g)
            #pragma unroll
            for (int r = 0; r < 16; ++r) {
                bmin[g][r] = fminf(bmin[g][r], acc[g][r]);
                fm         = fminf(fm, acc[g][r]);
            }
        // clamp >=0 so uint ordering == float ordering; lanes l/l+32 share
        // an address (2-way): no-return ds_min, pipelined
        atomicMin(&fbuf[b][l31], __float_as_uint(fmaxf(fm, 0.0f)));
    }
    __syncthreads();  // fbuf atomics from all waves complete

    // flush forward mins (values are sq/2; finalize applies the 2x)
    {
        int i = tid & 255;  // exactly BB*32 = 256 items
        atomicMin(&fwd[(size_t)(i >> 5) * MM + m0 + (i & 31)], fbuf[i >> 5][i & 31]);
    }

    // backward: sqrt(2 * clamp(min sq/2)), block-reduce, one store/block
    float s = 0.0f;
    #pragma unroll
    for (int g = 0; g < 2; ++g)
        #pragma unroll
        for (int r = 0; r < 16; ++r)
            s += sqrtf(2.0f * fmaxf(bmin[g][r], 0.0f));
    #pragma unroll
    for (int off = 32; off; off >>= 1) s += __shfl_down(s, off, 64);
    if (lane == 0) red[wave] = s;
    __syncthreads();
    if (tid == 0) bpart[id] = red[0] + red[1] + red[2] + red[3];
}

// Finalize: 32 blocks x 256 threads. fwd holds min sq/2 -> dist = sqrt(2v).
__global__ __launch_bounds__(256)
void finalize_kernel(const unsigned int* __restrict__ fwd,
                     const float* __restrict__ bpart,
                     float* __restrict__ bsum, float* __restrict__ fsum,
                     unsigned int* __restrict__ counter, float* __restrict__ out) {
    __shared__ float redf[4], redb[4];
    __shared__ int isLast;
    const int tid = threadIdx.x, lane = tid & 63, wave = tid >> 6;
    const int gtid = blockIdx.x * 256 + tid;
    uint4 u = ((const uint4*)fwd)[gtid];
    float sf = sqrtf(2.0f * __uint_as_float(u.x)) + sqrtf(2.0f * __uint_as_float(u.y)) +
               sqrtf(2.0f * __uint_as_float(u.z)) + sqrtf(2.0f * __uint_as_float(u.w));
    float sb = (gtid < 2048) ? bpart[gtid] : 0.0f;   // 2048 main blocks
    #pragma unroll
    for (int off = 32; off; off >>= 1) {
        sf += __shfl_down(sf, off, 64);
        sb += __shfl_down(sb, off, 64);
    }
    if (lane == 0) { redf[wave] = sf; redb[wave] = sb; }
    __syncthreads();
    if (tid == 0) {
        atomicAdd(fsum, redf[0] + redf[1] + redf[2] + redf[3]);
        atomicAdd(bsum, redb[0] + redb[1] + redb[2] + redb[3]);
        __threadfence();
        unsigned int c = atomicAdd(counter, 1u);
        isLast = (c == gridDim.x - 1) ? 1 : 0;
        if (isLast) {
            __threadfence();
            float fs = __hip_atomic_load(fsum, __ATOMIC_RELAXED,
                                         __HIP_MEMORY_SCOPE_AGENT);
            float bs = __hip_atomic_load(bsum, __ATOMIC_RELAXED,
                                         __HIP_MEMORY_SCOPE_AGENT);
            out[0] = fs / (float)(BB * MM) + bs / ((float)NN * (float)MM);
        }
    }
}

extern "C" void kernel_launch(void* const* d_in, const int* in_sizes, int n_in,
                              void* d_out, int out_size, void* d_ws, size_t ws_size,
                              hipStream_t stream) {
    const float* x = (const float*)d_in[0];  // (B,N,D)
    const float* y = (const float*)d_in[1];  // (B,M,D)
    float* out = (float*)d_out;

    char* w = (char*)d_ws;
    unsigned char* xq = (unsigned char*)(w);               // 4 MB fp8 (frag order)
    unsigned char* yq = (unsigned char*)(w + 4194304);     // 4 MB fp8, NEGATED
    float*    x2 = (float*)(w + 8388608);                  // 128 KB (x2/2)
    float*    y2 = (float*)(w + 8519680);                  // 128 KB (y2/2)
    unsigned int* fwd = (unsigned int*)(w + 8650752);      // 128 KB (min sq/2)
    float*    bpart = (float*)(w + 8781824);               // 8 KB (2048 blocks)
    float*    bsum = (float*)(w + 8798208);                // 4 B
    float*    fsum = (float*)(w + 8798212);                // 4 B
    unsigned int* counter = (unsigned int*)(w + 8798216);  // 4 B

    prep_all<<<2048, 256, 0, stream>>>(x, y, xq, yq, x2, y2,
                                       fwd, bsum, fsum, counter);
    chamfer_main<<<2048, 256, 0, stream>>>(xq, yq, x2, y2, fwd, bpart);
    finalize_kernel<<<32, 256, 0, stream>>>(fwd, bpart, bsum, fsum, counter, out);
}

// Round 12
// 107.428 us; speedup vs baseline: 1.0551x; 1.0466x over previous
//
#include <hip/hip_runtime.h>
#include <hip/hip_fp8.h>

#define BB 8
#define NN 4096
#define MM 4096
#define DD 128

typedef float f32x4  __attribute__((ext_vector_type(4)));
typedef float f32x16 __attribute__((ext_vector_type(16)));
typedef int   i32x4  __attribute__((ext_vector_type(4)));
typedef int   i32x8  __attribute__((ext_vector_type(8)));

// ---------------------------------------------------------------------------
// R31 (3rd submit — R31/R32 benches never ran: GPUAcquisitionTimeout x2).
// The untried cell — LOW TRAFFIC x HIGH WAVE DENSITY. Cross-round fit:
// time ~= fragment_traffic / rate(waves_per_CU), rate saturating ~15.2 TB/s
// at 16 waves/CU (R26), only 8.8 at 8 w/CU (R25). R25 had low traffic
// (384MB) at 8 w/CU; R26 had 16 w/CU at 640MB; both ~42-43us. This kernel:
// 8-wave 512-thread blocks, 256n x 64m, all-y-staged (64KB shared by 8
// waves) -> 2 blocks/CU = 16 waves/CU with traffic x=256MB + y=64MB =
// 320MB. Predicted main ~= 320/15.2 ~= 21us + overhead.
// This is R24's EXACT geometry (correctness-verified, absmax 0) minus its
// failure cause: R24's fx ring-of-2 source-dbuf (+32 VGPR) pushed state to
// ~160 vs the 128 cap of (512,4) -> 118MB scratch spill. R28 proved
// prefetch depth is perf-neutral -> x loads are point-of-use here; state
// ~= acc 32 + bmin 32 + transients ~= 115 < 128. Tripwires: WRITE_SIZE
// (spill -> ~118MB) and first-dispatch anomaly (scratch warmup).
//
// Fixed harness cost: ~44us 256MiB fillBufferAligned re-poison in-window.
//
// R19-29 retained: fragment-ordered fp8, HALF-norms + negated y (acc=sq/2),
// mfma_scale_f32_32x32x64_f8f6f4 identity scale 127, balanced per-XCD patch
// (3MB < 4MB XCD L2), coalesced LDS-staged prep, all-y-staged prologue,
// barrier-free batch loop.
// LESSONS: merged finalize regresses (R11/12/15/16); cooperative launch
// fails (R14); prep transport not the gap (R21); per-batch barriers ~2x at
// low occ (R23); spills catastrophic (R24); TLP alone null (R26); compiler
// sinks plain-HIP prefetch (R27); forced prefetch null (R28); per-work
// overhead halving null (R29).
// ---------------------------------------------------------------------------

typedef const __attribute__((address_space(1))) unsigned int* gas_ptr;
typedef __attribute__((address_space(3))) unsigned int* las_ptr;
static __device__ __forceinline__ void gload_lds16(const unsigned char* g,
                                                   unsigned char* l) {
    __builtin_amdgcn_global_load_lds((gas_ptr)g, (las_ptr)l, 16, 0, 0);
}

// Prep v2 (R21, unchanged): 2048 blocks x 256 threads, one 32-row fragment
// group (4KB) per block; coalesced reads -> cvt -> LDS permute -> coalesced
// 16B stores. Also inits fwd/bsum/fsum/counter and writes half-norms.
__global__ __launch_bounds__(256)
void prep_all(const float* __restrict__ x, const float* __restrict__ y,
              unsigned char* __restrict__ xq, unsigned char* __restrict__ yq,
              float* __restrict__ x2, float* __restrict__ y2,
              unsigned int* __restrict__ fwd, float* __restrict__ bsum,
              float* __restrict__ fsum, unsigned int* __restrict__ counter) {
    __shared__ i32x4 lbuf[256];  // 4 KB fragment-ordered staging

    const int tid  = threadIdx.x;
    const int g    = blockIdx.x;
    const int gtid = g * 256 + tid;
    if (gtid < BB * MM) fwd[gtid] = 0x7f800000u;  // +inf bits
    if (gtid == 0) { *bsum = 0.0f; *fsum = 0.0f; *counter = 0u; }

    const int rl = tid >> 3;   // row within group (0..31)
    const int c  = tid & 7;    // 16-float chunk within row (0..7)

    const float* src;
    unsigned char* dst;
    float* sq;
    float sgn;
    int row;
    if (g < 1024) {
        src = x; dst = xq + (size_t)g * 4096; sq = x2; sgn = 1.0f;
        row = g * 32 + rl;
    } else {
        src = y; dst = yq + (size_t)(g - 1024) * 4096; sq = y2; sgn = -1.0f;
        row = (g - 1024) * 32 + rl;
    }

    const f32x4* base = (const f32x4*)(src + (size_t)row * DD + c * 16);
    f32x4 v[4];
    #pragma unroll
    for (int j = 0; j < 4; ++j) v[j] = base[j];

    float s = 0.0f;
    #pragma unroll
    for (int j = 0; j < 4; ++j)
        s += v[j].x * v[j].x + v[j].y * v[j].y + v[j].z * v[j].z + v[j].w * v[j].w;

    i32x4 d;
    #pragma unroll
    for (int j = 0; j < 4; ++j) {
        unsigned int dj = (unsigned int)__builtin_amdgcn_cvt_pk_fp8_f32(
            sgn * v[j].x, sgn * v[j].y, 0, false);
        dj = (unsigned int)__builtin_amdgcn_cvt_pk_fp8_f32(
            sgn * v[j].z, sgn * v[j].w, (int)dj, true);
        d[j] = (int)dj;
    }

    const int lds_off = (c >> 2) * 2048 + ((c >> 1) & 1) * 1024
                      + rl * 32 + (c & 1) * 16;
    *(i32x4*)((char*)lbuf + lds_off) = d;

    #pragma unroll
    for (int m = 4; m; m >>= 1) s += __shfl_xor(s, m, 64);
    if (c == 0) sq[row] = 0.5f * s;

    __syncthreads();
    *(i32x4*)(dst + (size_t)tid * 16) = lbuf[tid];
}

// ---------------------------------------------------------------------------
// Main v10: 1024 blocks (256n x 64m), 8 waves of 32n x 64m, all-y-staged
// prologue (64KB shared by 8 waves -> 16 w/CU), barrier-free loop,
// point-of-use x loads (no ring -> no spill).
// ---------------------------------------------------------------------------
__global__ __launch_bounds__(512, 4)
void chamfer_main(const unsigned char* __restrict__ xq, const unsigned char* __restrict__ yq,
                  const float* __restrict__ x2, const float* __restrict__ y2,
                  unsigned int* __restrict__ fwd, float* __restrict__ bpart) {
    __shared__ float x2s[BB][256];            // 8 KB
    __shared__ float y2s[BB][64];             // 2 KB
    __shared__ unsigned int fbuf[BB][64];     // 2 KB
    __shared__ unsigned char ybuf[BB][8192];  // 64 KB: ALL batches of y-frags
    __shared__ float red[8];

    const int tid   = threadIdx.x;
    const int lane  = tid & 63;
    const int wave  = tid >> 6;    // 0..7
    const int lhalf = lane >> 5;
    const int l31   = lane & 31;

    const int id  = blockIdx.x;
    const int xcd = id & 7;
    const int j   = id >> 3;                   // 0..127
    const int nb  = (xcd >> 1) * 4 + (j & 3);  // 0..15  (256 n each)
    const int mb  = (xcd & 1) * 32 + (j >> 2); // 0..63  (64 m each)
    const int n0b = nb * 256;
    const int n0w = n0b + wave * 32;
    const int m0  = mb * 64;

    // x fragment base (per-wave, point-of-use loads)
    const size_t laneoff = (size_t)lhalf * 1024 + (size_t)l31 * 32;
    const unsigned char* xbase = xq + (size_t)(n0w >> 5) * 4096 + laneoff;

    // y staging, source-swizzled so LDS is dense (R24-verified formula):
    // wave = chunk c -> (t,i,lh) = (c>>2,(c>>1)&1,c&1); lane -> l31*32+hh*16
    const size_t ysw = (size_t)(wave >> 2) * 4096 + (size_t)((wave >> 1) & 1) * 2048
                     + (size_t)(wave & 1) * 1024 + (size_t)l31 * 32
                     + (size_t)lhalf * 16;
    const unsigned char* ybase = yq + (size_t)mb * 8192 + ysw;

    // prologue: stage ALL 8 batches of y (1 gload_lds per wave per batch)
    #pragma unroll
    for (int b = 0; b < BB; ++b)
        gload_lds16(ybase + ((size_t)b << 19), &ybuf[b][wave * 1024]);

    for (int i = tid; i < BB * 256; i += 512)
        x2s[i >> 8][i & 255] = x2[(size_t)(i >> 8) * NN + n0b + (i & 255)];
    {
        int i = tid;  // exactly BB*64 = 512 items
        y2s[i >> 6][i & 63] = y2[(size_t)(i >> 6) * MM + m0 + (i & 63)];
        ((unsigned int*)fbuf)[i] = 0x7f800000u;
    }
    __syncthreads();  // the ONLY barrier before the loop (drains staging)

    const float INF = __builtin_inff();
    float bmin[2][16];  // [m-tile][reg] running min of acc = sq/2
    #pragma unroll
    for (int t = 0; t < 2; ++t)
        #pragma unroll
        for (int r = 0; r < 16; ++r) bmin[t][r] = INF;

    const int rb0 = lhalf * 1024 + l31 * 16;  // dense y read base

    #pragma unroll 2
    for (int b = 0; b < BB; ++b) {
        // x for batch b: point-of-use (NO ring — R24's +32 VGPR dbuf spilled;
        // R28 proved prefetch depth perf-neutral at this wave density)
        const unsigned char* xb = xbase + ((size_t)b << 19);
        i32x4 fx[2][2];
        #pragma unroll
        for (int i = 0; i < 2; ++i)
            #pragma unroll
            for (int hh = 0; hh < 2; ++hh)
                fx[i][hh] = *(const i32x4*)(xb + i * 2048 + hh * 16);

        // acc seeds: (x2+y2)/2 -> MFMA (neg-y fp8) yields acc = sq/2
        // C/D: col = l31, row = (r&3) + 8*(r>>2) + 4*lhalf
        float y2v[2];
        y2v[0] = y2s[b][l31];
        y2v[1] = y2s[b][32 + l31];
        f32x16 acc[2];
        #pragma unroll
        for (int q = 0; q < 4; ++q) {
            f32x4 xv = *(const f32x4*)&x2s[b][wave * 32 + lhalf * 4 + q * 8];
            #pragma unroll
            for (int t = 0; t < 2; ++t)
                #pragma unroll
                for (int e = 0; e < 4; ++e)
                    acc[t][q * 4 + e] = xv[e] + y2v[t];
        }

        #pragma unroll
        for (int i = 0; i < 2; ++i) {
            i32x8 av = __builtin_shufflevector(fx[i][0], fx[i][1],
                                               0, 1, 2, 3, 4, 5, 6, 7);
            #pragma unroll
            for (int t = 0; t < 2; ++t) {
                const unsigned char* yb = &ybuf[b][t * 4096 + i * 2048 + rb0];
                i32x4 lo = *(const i32x4*)(yb);
                i32x4 hi = *(const i32x4*)(yb + 512);
                i32x8 bv = __builtin_shufflevector(lo, hi, 0, 1, 2, 3, 4, 5, 6, 7);
                acc[t] = __builtin_amdgcn_mfma_scale_f32_32x32x64_f8f6f4(
                    av, bv, acc[t], 0, 0, 0, 127, 0, 127);
            }
        }

        // epilogue: pure fmin (acc IS sq/2)
        float fm[2] = {INF, INF};
        #pragma unroll
        for (int t = 0; t < 2; ++t)
            #pragma unroll
            for (int r = 0; r < 16; ++r) {
                bmin[t][r] = fminf(bmin[t][r], acc[t][r]);
                fm[t]      = fminf(fm[t], acc[t][r]);
            }
        #pragma unroll
        for (int t = 0; t < 2; ++t)
            atomicMin(&fbuf[b][t * 32 + l31],
                      __float_as_uint(fmaxf(fm[t], 0.0f)));
    }
    __syncthreads();  // fbuf atomics from all waves complete

    // flush forward mins (values are sq/2; finalize applies the 2x)
    {
        int i = tid;  // exactly BB*64 = 512 items
        atomicMin(&fwd[(size_t)(i >> 6) * MM + m0 + (i & 63)], fbuf[i >> 6][i & 63]);
    }

    // backward: sqrt(2 * clamp(min sq/2)), block-reduce, one store/block
    float s = 0.0f;
    #pragma unroll
    for (int t = 0; t < 2; ++t)
        #pragma unroll
        for (int r = 0; r < 16; ++r)
            s += sqrtf(2.0f * fmaxf(bmin[t][r], 0.0f));
    #pragma unroll
    for (int off = 32; off; off >>= 1) s += __shfl_down(s, off, 64);
    if (lane == 0) red[wave] = s;
    __syncthreads();
    if (tid == 0)
        bpart[id] = red[0] + red[1] + red[2] + red[3]
                  + red[4] + red[5] + red[6] + red[7];
}

// Finalize: 32 blocks x 256 threads. fwd holds min sq/2 -> dist = sqrt(2v).
__global__ __launch_bounds__(256)
void finalize_kernel(const unsigned int* __restrict__ fwd,
                     const float* __restrict__ bpart,
                     float* __restrict__ bsum, float* __restrict__ fsum,
                     unsigned int* __restrict__ counter, float* __restrict__ out) {
    __shared__ float redf[4], redb[4];
    __shared__ int isLast;
    const int tid = threadIdx.x, lane = tid & 63, wave = tid >> 6;
    const int gtid = blockIdx.x * 256 + tid;
    uint4 u = ((const uint4*)fwd)[gtid];
    float sf = sqrtf(2.0f * __uint_as_float(u.x)) + sqrtf(2.0f * __uint_as_float(u.y)) +
               sqrtf(2.0f * __uint_as_float(u.z)) + sqrtf(2.0f * __uint_as_float(u.w));
    float sb = (gtid < 1024) ? bpart[gtid] : 0.0f;   // 1024 main blocks
    #pragma unroll
    for (int off = 32; off; off >>= 1) {
        sf += __shfl_down(sf, off, 64);
        sb += __shfl_down(sb, off, 64);
    }
    if (lane == 0) { redf[wave] = sf; redb[wave] = sb; }
    __syncthreads();
    if (tid == 0) {
        atomicAdd(fsum, redf[0] + redf[1] + redf[2] + redf[3]);
        atomicAdd(bsum, redb[0] + redb[1] + redb[2] + redb[3]);
        __threadfence();
        unsigned int c = atomicAdd(counter, 1u);
        isLast = (c == gridDim.x - 1) ? 1 : 0;
        if (isLast) {
            __threadfence();
            float fs = __hip_atomic_load(fsum, __ATOMIC_RELAXED,
                                         __HIP_MEMORY_SCOPE_AGENT);
            float bs = __hip_atomic_load(bsum, __ATOMIC_RELAXED,
                                         __HIP_MEMORY_SCOPE_AGENT);
            out[0] = fs / (float)(BB * MM) + bs / ((float)NN * (float)MM);
        }
    }
}

extern "C" void kernel_launch(void* const* d_in, const int* in_sizes, int n_in,
                              void* d_out, int out_size, void* d_ws, size_t ws_size,
                              hipStream_t stream) {
    const float* x = (const float*)d_in[0];  // (B,N,D)
    const float* y = (const float*)d_in[1];  // (B,M,D)
    float* out = (float*)d_out;

    char* w = (char*)d_ws;
    unsigned char* xq = (unsigned char*)(w);               // 4 MB fp8 (frag order)
    unsigned char* yq = (unsigned char*)(w + 4194304);     // 4 MB fp8, NEGATED
    float*    x2 = (float*)(w + 8388608);                  // 128 KB (x2/2)
    float*    y2 = (float*)(w + 8519680);                  // 128 KB (y2/2)
    unsigned int* fwd = (unsigned int*)(w + 8650752);      // 128 KB (min sq/2)
    float*    bpart = (float*)(w + 8781824);               // 4 KB (1024 blocks)
    float*    bsum = (float*)(w + 8798208);                // 4 B
    float*    fsum = (float*)(w + 8798212);                // 4 B
    unsigned int* counter = (unsigned int*)(w + 8798216);  // 4 B

    prep_all<<<2048, 256, 0, stream>>>(x, y, xq, yq, x2, y2,
                                       fwd, bsum, fsum, counter);
    chamfer_main<<<1024, 512, 0, stream>>>(xq, yq, x2, y2, fwd, bpart);
    finalize_kernel<<<32, 256, 0, stream>>>(fwd, bpart, bsum, fsum, counter, out);
}